// Round 8
// baseline (195.338 us; speedup 1.0000x reference)
//
#include <hip/hip_runtime.h>
#include <hip/hip_bf16.h>

// GraphAttentionLayer = flash attention with adjacency mask.
// B=4, N=4096, D_in=128, H=64 (QK dim), D_out=128 (V dim).
// Precision: scores need ~f32 accuracy -> Whs/Wht GEMM and QK^T use bf16
// hi+lo 3-term MFMA. P, V, partial-O single bf16.
// Structure (round-5 proven, 62.7us): split-K flash SPLIT=4 (512 blocks =
// 2/CU, register-capped: ~116 arch VGPR + 64 acc), single-buffered LDS with
// 2 barriers/tile (writes own a short phase; compute phase is read-only --
// round-7 showed merging them regresses). Wave owns 32 q-rows (two 16-q
// groups) so each K/V LDS fragment feeds 2 MFMAs. Swapped QK^T (lane lc =
// q-row -> lane-local softmax); V slot-permutation pre-applied in prep's
// WhcT write so attn stages V with 4 straight b128 copies; PV A-operand
// packed in-register via v_cvt_pk_bf16_f32. Softmax in log2 domain (log2e
// folded into Ws) + exact defer-rescale (THR=4 in log2 domain).
#define NTOK 4096
#define BATCH 4
#define DIN 128
#define DHID 64
#define DOUT 128
#define NWRD (NTOK / 32)
#define SPLIT 4
#define ITERS (NTOK / SPLIT / 64)  // 16 key-tiles per split
#define NEG_BIG -9.0e15f
#define LOG2E 1.44269504088896340736f

typedef short short8 __attribute__((ext_vector_type(8)));
typedef float floatx4 __attribute__((ext_vector_type(4)));

static __device__ __forceinline__ unsigned short f2bf(float f) {
    unsigned int u = __builtin_bit_cast(unsigned int, f);
    u = (u + 0x7fffu + ((u >> 16) & 1u)) >> 16;
    return (unsigned short)u;
}
static __device__ __forceinline__ float bf2f(unsigned short s) {
    unsigned int u = ((unsigned int)s) << 16;
    return __builtin_bit_cast(float, u);
}
// pack two f32 -> (lo,hi) bf16 in one u32
static __device__ __forceinline__ unsigned int pk2(float lo, float hi) {
    unsigned int r;
    asm("v_cvt_pk_bf16_f32 %0, %1, %2" : "=v"(r) : "v"(lo), "v"(hi));
    return r;
}

static __device__ __forceinline__ floatx4 mfma16(short8 a, short8 b, floatx4 c) {
    // v_mfma_f32_16x16x32_bf16: A row = lane&15, k = 8*(lane>>4)+{0..7}
    //                           B col = lane&15, k = 8*(lane>>4)+{0..7}
    //                           D col = lane&15, row = 4*(lane>>4)+reg
    return __builtin_amdgcn_mfma_f32_16x16x32_bf16(a, b, c, 0, 0, 0);
}

// ---------------------------------------------------------------- pack_adj
__global__ __launch_bounds__(256) void pack_adj_kernel(const int* __restrict__ adj,
                                                       unsigned int* __restrict__ bits) {
    int w = blockIdx.x * 256 + threadIdx.x;
    const int4* p = reinterpret_cast<const int4*>(adj) + (size_t)w * 8;
    unsigned int m = 0;
#pragma unroll
    for (int i = 0; i < 8; ++i) {
        int4 v = p[i];
        m |= (v.x > 0 ? 1u : 0u) << (4 * i + 0);
        m |= (v.y > 0 ? 1u : 0u) << (4 * i + 1);
        m |= (v.z > 0 ? 1u : 0u) << (4 * i + 2);
        m |= (v.w > 0 ? 1u : 0u) << (4 * i + 3);
    }
    bits[w] = m;
}

// ---------------------------------------------------------------- conv_w
// Ws cols pre-scaled by log2e so QK^T scores land in log2 domain.
__global__ __launch_bounds__(256) void conv_w_kernel(const float* __restrict__ Ws,
                                                     const float* __restrict__ Wt,
                                                     const float* __restrict__ Wc,
                                                     unsigned short* __restrict__ WT_hi,
                                                     unsigned short* __restrict__ WT_lo) {
    int idx = blockIdx.x * 256 + threadIdx.x;
    int k = idx >> 8, col = idx & 255;
    float w;
    if (col < 64) w = Ws[k * DHID + col] * LOG2E;
    else if (col < 128) w = Wt[k * DHID + (col - 64)];
    else w = Wc[k * DOUT + (col - 128)];
    unsigned short hi = f2bf(w);
    WT_hi[col * DIN + k] = hi;
    if (col < 128) WT_lo[col * DIN + k] = f2bf(w - bf2f(hi));
}

// ---------------------------------------------------------------- prep
// WhcT is written with the V slot permutation pre-applied per 32-key group:
// key k -> slot = (k&~31) | (bit3(k)<<4) | (bit2(k)<<3) | (bit4(k)<<2) | (k&3)
// so attn's V staging is a straight contiguous copy. (HW-verified in R7.)
__global__ __launch_bounds__(256) void prep_kernel(const float* __restrict__ h,
                                                   const unsigned short* __restrict__ WT_hi,
                                                   const unsigned short* __restrict__ WT_lo,
                                                   unsigned short* __restrict__ Whs_hi,
                                                   unsigned short* __restrict__ Whs_lo,
                                                   unsigned short* __restrict__ Wht_hi,
                                                   unsigned short* __restrict__ Wht_lo,
                                                   unsigned short* __restrict__ WhcT) {
    int tid = threadIdx.x;
    int b = blockIdx.y;
    int w = tid >> 6, lane = tid & 63, lg = lane >> 4, lc = lane & 15;
    int n0 = blockIdx.x * 16;
    const float* hrow = h + (size_t)(b * NTOK + n0 + lc) * DIN;

    short8 ah[4], al[4];
#pragma unroll
    for (int ks = 0; ks < 4; ++ks) {
        float4 f0 = *reinterpret_cast<const float4*>(hrow + ks * 32 + lg * 8);
        float4 f1 = *reinterpret_cast<const float4*>(hrow + ks * 32 + lg * 8 + 4);
        float x[8] = {f0.x, f0.y, f0.z, f0.w, f1.x, f1.y, f1.z, f1.w};
        short8 hh, ll;
#pragma unroll
        for (int j = 0; j < 8; ++j) {
            unsigned short hb = f2bf(x[j]);
            hh[j] = (short)hb;
            ll[j] = (short)f2bf(x[j] - bf2f(hb));
        }
        ah[ks] = hh;
        al[ks] = ll;
    }

#pragma unroll
    for (int ci = 0; ci < 4; ++ci) {
        int ct = w * 4 + ci;
        int col = ct * 16 + lc;
        const unsigned short* bbase = WT_hi + (size_t)col * DIN;
        const unsigned short* lbase = WT_lo + (size_t)col * DIN;
        floatx4 acc = {0.f, 0.f, 0.f, 0.f};
#pragma unroll
        for (int ks = 0; ks < 4; ++ks) {
            short8 bh = *reinterpret_cast<const short8*>(bbase + ks * 32 + lg * 8);
            acc = mfma16(ah[ks], bh, acc);
            if (w < 2) {
                short8 bl = *reinterpret_cast<const short8*>(lbase + ks * 32 + lg * 8);
                acc = mfma16(ah[ks], bl, acc);
                acc = mfma16(al[ks], bh, acc);
            }
        }
        int nr = n0 + 4 * lg;
        if (w == 0) {
#pragma unroll
            for (int r = 0; r < 4; ++r) {
                float v = acc[r];
                unsigned short hb = f2bf(v);
                size_t o = (size_t)(b * NTOK + nr + r) * DHID + col;
                Whs_hi[o] = hb;
                Whs_lo[o] = f2bf(v - bf2f(hb));
            }
        } else if (w == 1) {
#pragma unroll
            for (int r = 0; r < 4; ++r) {
                float v = acc[r];
                unsigned short hb = f2bf(v);
                size_t o = (size_t)(b * NTOK + nr + r) * DHID + (col - 64);
                Wht_hi[o] = hb;
                Wht_lo[o] = f2bf(v - bf2f(hb));
            }
        } else {
            // permuted destination column base (keys nr..nr+3, t = r stays)
            int pcol = (nr & ~31) | ((nr & 8) << 1) | ((nr & 4) << 1) | ((nr & 16) >> 2);
            unsigned int p01 = (unsigned int)f2bf(acc[0]) | ((unsigned int)f2bf(acc[1]) << 16);
            unsigned int p23 = (unsigned int)f2bf(acc[2]) | ((unsigned int)f2bf(acc[3]) << 16);
            unsigned int* dst =
                reinterpret_cast<unsigned int*>(&WhcT[(size_t)(b * DOUT + col - 128) * NTOK + pcol]);
            dst[0] = p01;
            dst[1] = p23;
        }
    }
}

// ---------------------------------------------------------------- attn (split-K)
// grid (N/128, B, SPLIT), 256 thr, 2 blocks/CU. Wave owns 32 q-rows (groups
// A: q0+lc, B: q0+16+lc). s[kc][r] = score(q, key=16kc+4lg+r), log2 domain.
// Single-buffered LDS, two barriers/tile (write phase separate from compute).
__global__ __launch_bounds__(256, 2) void attn_kernel(const unsigned short* __restrict__ Whs_hi,
                                                      const unsigned short* __restrict__ Whs_lo,
                                                      const unsigned short* __restrict__ Wht_hi,
                                                      const unsigned short* __restrict__ Wht_lo,
                                                      const unsigned short* __restrict__ WhcT,
                                                      const unsigned int* __restrict__ bits,
                                                      unsigned short* __restrict__ po,
                                                      float* __restrict__ pm,
                                                      float* __restrict__ pl) {
    __shared__ unsigned short Kh_lds[64][72];
    __shared__ unsigned short Kl_lds[64][72];
    __shared__ unsigned short V_lds[128][72];  // [d][slot] (slots pre-permuted)

    int tid = threadIdx.x;
    int b = blockIdx.y;
    int split = blockIdx.z;
    int kbase = split * (ITERS * 64);
    int lane = tid & 63, lg = lane >> 4, lc = lane & 15;
    int q0 = blockIdx.x * 128 + (tid >> 6) * 32;
    int nA = q0 + lc, nB = q0 + 16 + lc;

    const unsigned short* qAH = Whs_hi + (size_t)(b * NTOK + nA) * DHID;
    const unsigned short* qAL = Whs_lo + (size_t)(b * NTOK + nA) * DHID;
    const unsigned short* qBH = Whs_hi + (size_t)(b * NTOK + nB) * DHID;
    const unsigned short* qBL = Whs_lo + (size_t)(b * NTOK + nB) * DHID;
    short8 qAh0 = *reinterpret_cast<const short8*>(qAH + lg * 8);
    short8 qAh1 = *reinterpret_cast<const short8*>(qAH + 32 + lg * 8);
    short8 qAl0 = *reinterpret_cast<const short8*>(qAL + lg * 8);
    short8 qAl1 = *reinterpret_cast<const short8*>(qAL + 32 + lg * 8);
    short8 qBh0 = *reinterpret_cast<const short8*>(qBH + lg * 8);
    short8 qBh1 = *reinterpret_cast<const short8*>(qBH + 32 + lg * 8);
    short8 qBl0 = *reinterpret_cast<const short8*>(qBL + lg * 8);
    short8 qBl1 = *reinterpret_cast<const short8*>(qBL + 32 + lg * 8);

    floatx4 o0[8], o1[8];
#pragma unroll
    for (int dt = 0; dt < 8; ++dt) {
        o0[dt] = (floatx4){0.f, 0.f, 0.f, 0.f};
        o1[dt] = (floatx4){0.f, 0.f, 0.f, 0.f};
    }
    float mA = NEG_BIG, lA = 0.f, mB = NEG_BIG, lB = 0.f;

    int kkey = tid >> 2, koff = (tid & 3) * 16;
    int vd = tid >> 1, va = tid & 1;

    short8 krH0, krH1, krL0, krL1, vr0, vr1, vr2, vr3;
    unsigned int mwA0, mwA1, mwB0, mwB1;

    {  // prologue: load tile 0
        int kb = kbase;
        const unsigned short* ksrcH = Wht_hi + (size_t)(b * NTOK + kb + kkey) * DHID + koff;
        const unsigned short* ksrcL = Wht_lo + (size_t)(b * NTOK + kb + kkey) * DHID + koff;
        krH0 = *reinterpret_cast<const short8*>(ksrcH);
        krH1 = *reinterpret_cast<const short8*>(ksrcH + 8);
        krL0 = *reinterpret_cast<const short8*>(ksrcL);
        krL1 = *reinterpret_cast<const short8*>(ksrcL + 8);
        const unsigned short* vsrc = WhcT + (size_t)(b * DOUT + vd) * NTOK + kb + va * 32;
        vr0 = *reinterpret_cast<const short8*>(vsrc);
        vr1 = *reinterpret_cast<const short8*>(vsrc + 8);
        vr2 = *reinterpret_cast<const short8*>(vsrc + 16);
        vr3 = *reinterpret_cast<const short8*>(vsrc + 24);
        mwA0 = bits[nA * NWRD + (kb >> 5)];
        mwA1 = bits[nA * NWRD + (kb >> 5) + 1];
        mwB0 = bits[nB * NWRD + (kb >> 5)];
        mwB1 = bits[nB * NWRD + (kb >> 5) + 1];
    }

    for (int it = 0; it < ITERS; ++it) {
        __syncthreads();  // previous tile's compute done
        *reinterpret_cast<short8*>(&Kh_lds[kkey][koff]) = krH0;
        *reinterpret_cast<short8*>(&Kh_lds[kkey][koff + 8]) = krH1;
        *reinterpret_cast<short8*>(&Kl_lds[kkey][koff]) = krL0;
        *reinterpret_cast<short8*>(&Kl_lds[kkey][koff + 8]) = krL1;
        // V staging: straight copy (slots pre-permuted in WhcT by prep)
        *reinterpret_cast<short8*>(&V_lds[vd][va * 32]) = vr0;
        *reinterpret_cast<short8*>(&V_lds[vd][va * 32 + 8]) = vr1;
        *reinterpret_cast<short8*>(&V_lds[vd][va * 32 + 16]) = vr2;
        *reinterpret_cast<short8*>(&V_lds[vd][va * 32 + 24]) = vr3;
        __syncthreads();  // tile visible

        // S^T = K Q^T, hi/lo cross terms, both q-groups share the K fragments
        floatx4 s0[4], s1[4];
        __builtin_amdgcn_s_setprio(1);
#pragma unroll
        for (int kc = 0; kc < 4; ++kc) {
            short8 kh0 = *reinterpret_cast<const short8*>(&Kh_lds[kc * 16 + lc][lg * 8]);
            short8 kh1 = *reinterpret_cast<const short8*>(&Kh_lds[kc * 16 + lc][32 + lg * 8]);
            short8 kl0 = *reinterpret_cast<const short8*>(&Kl_lds[kc * 16 + lc][lg * 8]);
            short8 kl1 = *reinterpret_cast<const short8*>(&Kl_lds[kc * 16 + lc][32 + lg * 8]);
            floatx4 a0 = {0.f, 0.f, 0.f, 0.f};
            a0 = mfma16(kh0, qAh0, a0);
            a0 = mfma16(kh1, qAh1, a0);
            a0 = mfma16(kh0, qAl0, a0);
            a0 = mfma16(kh1, qAl1, a0);
            a0 = mfma16(kl0, qAh0, a0);
            a0 = mfma16(kl1, qAh1, a0);
            s0[kc] = a0;
            floatx4 a1 = {0.f, 0.f, 0.f, 0.f};
            a1 = mfma16(kh0, qBh0, a1);
            a1 = mfma16(kh1, qBh1, a1);
            a1 = mfma16(kh0, qBl0, a1);
            a1 = mfma16(kh1, qBl1, a1);
            a1 = mfma16(kl0, qBh0, a1);
            a1 = mfma16(kl1, qBh1, a1);
            s1[kc] = a1;
        }
        __builtin_amdgcn_s_setprio(0);

        // adjacency mask: key = 16kc+4lg+r -> word kc>>1, bit 16*(kc&1)+4lg+r
#pragma unroll
        for (int kc = 0; kc < 4; ++kc) {
            unsigned int wA = (kc & 2) ? mwA1 : mwA0;
            unsigned int wB = (kc & 2) ? mwB1 : mwB0;
#pragma unroll
            for (int r = 0; r < 4; ++r) {
                int bit = 16 * (kc & 1) + 4 * lg + r;
                if (!((wA >> bit) & 1u)) s0[kc][r] = NEG_BIG;
                if (!((wB >> bit) & 1u)) s1[kc][r] = NEG_BIG;
            }
        }

        // prefetch next tile (global -> reg, hidden under softmax+PV)
        if (it + 1 < ITERS) {
            int kb = kbase + (it + 1) * 64;
            const unsigned short* ksrcH = Wht_hi + (size_t)(b * NTOK + kb + kkey) * DHID + koff;
            const unsigned short* ksrcL = Wht_lo + (size_t)(b * NTOK + kb + kkey) * DHID + koff;
            krH0 = *reinterpret_cast<const short8*>(ksrcH);
            krH1 = *reinterpret_cast<const short8*>(ksrcH + 8);
            krL0 = *reinterpret_cast<const short8*>(ksrcL);
            krL1 = *reinterpret_cast<const short8*>(ksrcL + 8);
            const unsigned short* vsrc = WhcT + (size_t)(b * DOUT + vd) * NTOK + kb + va * 32;
            vr0 = *reinterpret_cast<const short8*>(vsrc);
            vr1 = *reinterpret_cast<const short8*>(vsrc + 8);
            vr2 = *reinterpret_cast<const short8*>(vsrc + 16);
            vr3 = *reinterpret_cast<const short8*>(vsrc + 24);
            mwA0 = bits[nA * NWRD + (kb >> 5)];
            mwA1 = bits[nA * NWRD + (kb >> 5) + 1];
            mwB0 = bits[nB * NWRD + (kb >> 5)];
            mwB1 = bits[nB * NWRD + (kb >> 5) + 1];
        }

        // online softmax (log2 domain) with exact defer-rescale, group A
        {
            float vm = s0[0][0];
#pragma unroll
            for (int kc = 0; kc < 4; ++kc)
#pragma unroll
                for (int r = 0; r < 4; ++r) vm = fmaxf(vm, s0[kc][r]);
            vm = fmaxf(vm, __shfl_xor(vm, 16));
            vm = fmaxf(vm, __shfl_xor(vm, 32));
            bool skip = __all(vm <= mA + 4.0f);
            float mn = skip ? mA : fmaxf(mA, vm);
            float rs = 0.f;
#pragma unroll
            for (int kc = 0; kc < 4; ++kc)
#pragma unroll
                for (int r = 0; r < 4; ++r) {
                    float p = exp2f(s0[kc][r] - mn);
                    s0[kc][r] = p;
                    rs += p;
                }
            rs += __shfl_xor(rs, 16);
            rs += __shfl_xor(rs, 32);
            if (!skip) {
                float sc = exp2f(mA - mn);
                lA = lA * sc + rs;
                mA = mn;
                float sc4[4];
#pragma unroll
                for (int r = 0; r < 4; ++r) sc4[r] = __shfl(sc, (lane & 48) + 4 * lg + r);
#pragma unroll
                for (int dt = 0; dt < 8; ++dt)
#pragma unroll
                    for (int r = 0; r < 4; ++r) o0[dt][r] *= sc4[r];
            } else {
                lA += rs;
            }
        }
        // group B
        {
            float vm = s1[0][0];
#pragma unroll
            for (int kc = 0; kc < 4; ++kc)
#pragma unroll
                for (int r = 0; r < 4; ++r) vm = fmaxf(vm, s1[kc][r]);
            vm = fmaxf(vm, __shfl_xor(vm, 16));
            vm = fmaxf(vm, __shfl_xor(vm, 32));
            bool skip = __all(vm <= mB + 4.0f);
            float mn = skip ? mB : fmaxf(mB, vm);
            float rs = 0.f;
#pragma unroll
            for (int kc = 0; kc < 4; ++kc)
#pragma unroll
                for (int r = 0; r < 4; ++r) {
                    float p = exp2f(s1[kc][r] - mn);
                    s1[kc][r] = p;
                    rs += p;
                }
            rs += __shfl_xor(rs, 16);
            rs += __shfl_xor(rs, 32);
            if (!skip) {
                float sc = exp2f(mB - mn);
                lB = lB * sc + rs;
                mB = mn;
                float sc4[4];
#pragma unroll
                for (int r = 0; r < 4; ++r) sc4[r] = __shfl(sc, (lane & 48) + 4 * lg + r);
#pragma unroll
                for (int dt = 0; dt < 8; ++dt)
#pragma unroll
                    for (int r = 0; r < 4; ++r) o1[dt][r] *= sc4[r];
            } else {
                lB += rs;
            }
        }

        // pack PV A-operands in-register
        unsigned int pw[8];
        pw[0] = pk2(s0[0][0], s0[0][1]); pw[1] = pk2(s0[0][2], s0[0][3]);
        pw[2] = pk2(s0[1][0], s0[1][1]); pw[3] = pk2(s0[1][2], s0[1][3]);
        pw[4] = pk2(s0[2][0], s0[2][1]); pw[5] = pk2(s0[2][2], s0[2][3]);
        pw[6] = pk2(s0[3][0], s0[3][1]); pw[7] = pk2(s0[3][2], s0[3][3]);
        short8 paA0 = __builtin_bit_cast(short8, *reinterpret_cast<uint4*>(&pw[0]));
        short8 paA1 = __builtin_bit_cast(short8, *reinterpret_cast<uint4*>(&pw[4]));
        pw[0] = pk2(s1[0][0], s1[0][1]); pw[1] = pk2(s1[0][2], s1[0][3]);
        pw[2] = pk2(s1[1][0], s1[1][1]); pw[3] = pk2(s1[1][2], s1[1][3]);
        pw[4] = pk2(s1[2][0], s1[2][1]); pw[5] = pk2(s1[2][2], s1[2][3]);
        pw[6] = pk2(s1[3][0], s1[3][1]); pw[7] = pk2(s1[3][2], s1[3][3]);
        short8 paB0 = __builtin_bit_cast(short8, *reinterpret_cast<uint4*>(&pw[0]));
        short8 paB1 = __builtin_bit_cast(short8, *reinterpret_cast<uint4*>(&pw[4]));

        // O += P V  (B col = lc = d, k = permuted slots; vf shared by both qg)
        __builtin_amdgcn_s_setprio(1);
#pragma unroll
        for (int dt = 0; dt < 8; ++dt) {
            short8 vf0 = *reinterpret_cast<const short8*>(&V_lds[dt * 16 + lc][lg * 8]);
            o0[dt] = mfma16(paA0, vf0, o0[dt]);
            o1[dt] = mfma16(paB0, vf0, o1[dt]);
        }
#pragma unroll
        for (int dt = 0; dt < 8; ++dt) {
            short8 vf1 = *reinterpret_cast<const short8*>(&V_lds[dt * 16 + lc][32 + lg * 8]);
            o0[dt] = mfma16(paA1, vf1, o0[dt]);
            o1[dt] = mfma16(paB1, vf1, o1[dt]);
        }
        __builtin_amdgcn_s_setprio(0);
    }

    // epilogue (m in log2 domain): o rows are q = q0+16qg+4lg+r; state at lc
    {
        float m4[4], l4[4];
#pragma unroll
        for (int r = 0; r < 4; ++r) {
            int src = (lane & 48) + 4 * lg + r;
            m4[r] = __shfl(mA, src);
            l4[r] = __shfl(lA, src);
        }
#pragma unroll
        for (int r = 0; r < 4; ++r) {
            size_t row = (size_t)(split * BATCH + b) * NTOK + q0 + 4 * lg + r;
            unsigned short* prow = po + row * DOUT;
#pragma unroll
            for (int dt = 0; dt < 8; ++dt) prow[dt * 16 + lc] = f2bf(o0[dt][r]);
            if (lc == 0) {
                pm[row] = m4[r];
                pl[row] = l4[r];
            }
        }
#pragma unroll
        for (int r = 0; r < 4; ++r) {
            int src = (lane & 48) + 4 * lg + r;
            m4[r] = __shfl(mB, src);
            l4[r] = __shfl(lB, src);
        }
#pragma unroll
        for (int r = 0; r < 4; ++r) {
            size_t row = (size_t)(split * BATCH + b) * NTOK + q0 + 16 + 4 * lg + r;
            unsigned short* prow = po + row * DOUT;
#pragma unroll
            for (int dt = 0; dt < 8; ++dt) prow[dt * 16 + lc] = f2bf(o1[dt][r]);
            if (lc == 0) {
                pm[row] = m4[r];
                pl[row] = l4[r];
            }
        }
    }
}

// ---------------------------------------------------------------- merge
__global__ __launch_bounds__(256) void merge_kernel(const unsigned short* __restrict__ po,
                                                    const float* __restrict__ pm,
                                                    const float* __restrict__ pl,
                                                    float* __restrict__ out) {
    int idx = blockIdx.x * 256 + threadIdx.x;
    int d = idx & (DOUT - 1);
    size_t bn = (size_t)(idx >> 7);
    const size_t BN = (size_t)BATCH * NTOK;

    float ms[SPLIT];
#pragma unroll
    for (int s = 0; s < SPLIT; ++s) ms[s] = pm[s * BN + bn];
    float M = ms[0];
#pragma unroll
    for (int s = 1; s < SPLIT; ++s) M = fmaxf(M, ms[s]);
    float L = 0.f, acc = 0.f;
#pragma unroll
    for (int s = 0; s < SPLIT; ++s) {
        float e = exp2f(ms[s] - M);
        L += pl[s * BN + bn] * e;
        acc += bf2f(po[(s * BN + bn) * DOUT + d]) * e;
    }
    out[idx] = acc / L;
}

// ---------------------------------------------------------------- launch
extern "C" void kernel_launch(void* const* d_in, const int* in_sizes, int n_in,
                              void* d_out, int out_size, void* d_ws, size_t ws_size,
                              hipStream_t stream) {
    const float* h   = (const float*)d_in[0];
    const int*   adj = (const int*)d_in[1];
    const float* Ws  = (const float*)d_in[2];
    const float* Wt  = (const float*)d_in[3];
    const float* Wc  = (const float*)d_in[4];
    float* out = (float*)d_out;

    // workspace layout (~31 MiB)
    size_t nq = (size_t)BATCH * NTOK * DHID;
    unsigned short* Whs_hi = (unsigned short*)d_ws;                                // 2 MiB
    unsigned short* Whs_lo = Whs_hi + nq;                                          // 2 MiB
    unsigned short* Wht_hi = Whs_lo + nq;                                          // 2 MiB
    unsigned short* Wht_lo = Wht_hi + nq;                                          // 2 MiB
    unsigned short* WhcT   = Wht_lo + nq;                                          // 4 MiB
    unsigned int*   bits   = (unsigned int*)(WhcT + (size_t)BATCH * DOUT * NTOK);  // 2 MiB
    unsigned short* WT_hi  = (unsigned short*)(bits + (size_t)NTOK * NWRD);        // 64 KiB
    unsigned short* WT_lo  = WT_hi + 256 * DIN;                                    // 32 KiB
    unsigned short* po     = WT_lo + 128 * DIN;                                    // 16 MiB
    float*          pm     = (float*)(po + (size_t)SPLIT * BATCH * NTOK * DOUT);   // 256 KiB
    float*          pl     = pm + (size_t)SPLIT * BATCH * NTOK;                    // 256 KiB

    pack_adj_kernel<<<dim3(NTOK * NWRD / 256), dim3(256), 0, stream>>>(adj, bits);
    conv_w_kernel<<<dim3(128), dim3(256), 0, stream>>>(Ws, Wt, Wc, WT_hi, WT_lo);
    prep_kernel<<<dim3(NTOK / 16, BATCH), dim3(256), 0, stream>>>(
        h, WT_hi, WT_lo, Whs_hi, Whs_lo, Wht_hi, Wht_lo, WhcT);
    attn_kernel<<<dim3(NTOK / 128, BATCH, SPLIT), dim3(256), 0, stream>>>(
        Whs_hi, Whs_lo, Wht_hi, Wht_lo, WhcT, bits, po, pm, pl);
    merge_kernel<<<dim3(BATCH * NTOK * DOUT / 256), dim3(256), 0, stream>>>(po, pm, pl, out);
}

// Round 9
// 189.938 us; speedup vs baseline: 1.0284x; 1.0284x over previous
//
#include <hip/hip_runtime.h>
#include <hip/hip_bf16.h>

// GraphAttentionLayer = flash attention with adjacency mask.
// B=4, N=4096, D_in=128, H=64 (QK dim), D_out=128 (V dim).
// Precision: scores need ~f32 accuracy -> Whs/Wht GEMM and QK^T use bf16
// hi+lo 3-term MFMA. P, V, partial-O single bf16.
// Structure (round-5 proven schedule): split-K flash SPLIT=4 (512 blocks =
// 2/CU, register-capped: ~116 arch VGPR + 64 acc), single-buffered LDS with
// 2 barriers/tile (write phase separate from read-only compute phase; R7
// showed merging them regresses). Wave owns 32 q-rows (two 16-q groups) so
// each K/V LDS fragment feeds 2 MFMAs. Swapped QK^T (lane lc = q-row ->
// lane-local softmax); V slot-permutation pre-applied in prep's WhcT write;
// PV A-operand packed in-register via v_cvt_pk_bf16_f32.
// Softmax in log2 domain (log2e folded into Ws); exp2 is RAW v_exp_f32
// (R8 lesson: plain exp2f is a ~10-op precise libcall -> +9us; the
// hardware op is 1 instruction and is exactly what __expf uses anyway).
// Exact defer-rescale (THR=4 in log2 domain).
#define NTOK 4096
#define BATCH 4
#define DIN 128
#define DHID 64
#define DOUT 128
#define NWRD (NTOK / 32)
#define SPLIT 4
#define ITERS (NTOK / SPLIT / 64)  // 16 key-tiles per split
#define NEG_BIG -9.0e15f
#define LOG2E 1.44269504088896340736f

typedef short short8 __attribute__((ext_vector_type(8)));
typedef float floatx4 __attribute__((ext_vector_type(4)));

static __device__ __forceinline__ unsigned short f2bf(float f) {
    unsigned int u = __builtin_bit_cast(unsigned int, f);
    u = (u + 0x7fffu + ((u >> 16) & 1u)) >> 16;
    return (unsigned short)u;
}
static __device__ __forceinline__ float bf2f(unsigned short s) {
    unsigned int u = ((unsigned int)s) << 16;
    return __builtin_bit_cast(float, u);
}
// pack two f32 -> (lo,hi) bf16 in one u32
static __device__ __forceinline__ unsigned int pk2(float lo, float hi) {
    unsigned int r;
    asm("v_cvt_pk_bf16_f32 %0, %1, %2" : "=v"(r) : "v"(lo), "v"(hi));
    return r;
}
// raw hardware exp2 (v_exp_f32 computes 2^x) -- NOT exp2f (precise libcall)
static __device__ __forceinline__ float ex2(float x) {
    float r;
    asm("v_exp_f32 %0, %1" : "=v"(r) : "v"(x));
    return r;
}

static __device__ __forceinline__ floatx4 mfma16(short8 a, short8 b, floatx4 c) {
    // v_mfma_f32_16x16x32_bf16: A row = lane&15, k = 8*(lane>>4)+{0..7}
    //                           B col = lane&15, k = 8*(lane>>4)+{0..7}
    //                           D col = lane&15, row = 4*(lane>>4)+reg
    return __builtin_amdgcn_mfma_f32_16x16x32_bf16(a, b, c, 0, 0, 0);
}

// ---------------------------------------------------------------- pack_adj
__global__ __launch_bounds__(256) void pack_adj_kernel(const int* __restrict__ adj,
                                                       unsigned int* __restrict__ bits) {
    int w = blockIdx.x * 256 + threadIdx.x;
    const int4* p = reinterpret_cast<const int4*>(adj) + (size_t)w * 8;
    unsigned int m = 0;
#pragma unroll
    for (int i = 0; i < 8; ++i) {
        int4 v = p[i];
        m |= (v.x > 0 ? 1u : 0u) << (4 * i + 0);
        m |= (v.y > 0 ? 1u : 0u) << (4 * i + 1);
        m |= (v.z > 0 ? 1u : 0u) << (4 * i + 2);
        m |= (v.w > 0 ? 1u : 0u) << (4 * i + 3);
    }
    bits[w] = m;
}

// ---------------------------------------------------------------- conv_w
// Ws cols pre-scaled by log2e so QK^T scores land in log2 domain.
__global__ __launch_bounds__(256) void conv_w_kernel(const float* __restrict__ Ws,
                                                     const float* __restrict__ Wt,
                                                     const float* __restrict__ Wc,
                                                     unsigned short* __restrict__ WT_hi,
                                                     unsigned short* __restrict__ WT_lo) {
    int idx = blockIdx.x * 256 + threadIdx.x;
    int k = idx >> 8, col = idx & 255;
    float w;
    if (col < 64) w = Ws[k * DHID + col] * LOG2E;
    else if (col < 128) w = Wt[k * DHID + (col - 64)];
    else w = Wc[k * DOUT + (col - 128)];
    unsigned short hi = f2bf(w);
    WT_hi[col * DIN + k] = hi;
    if (col < 128) WT_lo[col * DIN + k] = f2bf(w - bf2f(hi));
}

// ---------------------------------------------------------------- prep
// WhcT is written with the V slot permutation pre-applied per 32-key group:
// key k -> slot = (k&~31) | (bit3(k)<<4) | (bit2(k)<<3) | (bit4(k)<<2) | (k&3)
// so attn's V staging is a straight contiguous copy. (HW-verified in R7/R8.)
__global__ __launch_bounds__(256) void prep_kernel(const float* __restrict__ h,
                                                   const unsigned short* __restrict__ WT_hi,
                                                   const unsigned short* __restrict__ WT_lo,
                                                   unsigned short* __restrict__ Whs_hi,
                                                   unsigned short* __restrict__ Whs_lo,
                                                   unsigned short* __restrict__ Wht_hi,
                                                   unsigned short* __restrict__ Wht_lo,
                                                   unsigned short* __restrict__ WhcT) {
    int tid = threadIdx.x;
    int b = blockIdx.y;
    int w = tid >> 6, lane = tid & 63, lg = lane >> 4, lc = lane & 15;
    int n0 = blockIdx.x * 16;
    const float* hrow = h + (size_t)(b * NTOK + n0 + lc) * DIN;

    short8 ah[4], al[4];
#pragma unroll
    for (int ks = 0; ks < 4; ++ks) {
        float4 f0 = *reinterpret_cast<const float4*>(hrow + ks * 32 + lg * 8);
        float4 f1 = *reinterpret_cast<const float4*>(hrow + ks * 32 + lg * 8 + 4);
        float x[8] = {f0.x, f0.y, f0.z, f0.w, f1.x, f1.y, f1.z, f1.w};
        short8 hh, ll;
#pragma unroll
        for (int j = 0; j < 8; ++j) {
            unsigned short hb = f2bf(x[j]);
            hh[j] = (short)hb;
            ll[j] = (short)f2bf(x[j] - bf2f(hb));
        }
        ah[ks] = hh;
        al[ks] = ll;
    }

#pragma unroll
    for (int ci = 0; ci < 4; ++ci) {
        int ct = w * 4 + ci;
        int col = ct * 16 + lc;
        const unsigned short* bbase = WT_hi + (size_t)col * DIN;
        const unsigned short* lbase = WT_lo + (size_t)col * DIN;
        floatx4 acc = {0.f, 0.f, 0.f, 0.f};
#pragma unroll
        for (int ks = 0; ks < 4; ++ks) {
            short8 bh = *reinterpret_cast<const short8*>(bbase + ks * 32 + lg * 8);
            acc = mfma16(ah[ks], bh, acc);
            if (w < 2) {
                short8 bl = *reinterpret_cast<const short8*>(lbase + ks * 32 + lg * 8);
                acc = mfma16(ah[ks], bl, acc);
                acc = mfma16(al[ks], bh, acc);
            }
        }
        int nr = n0 + 4 * lg;
        if (w == 0) {
#pragma unroll
            for (int r = 0; r < 4; ++r) {
                float v = acc[r];
                unsigned short hb = f2bf(v);
                size_t o = (size_t)(b * NTOK + nr + r) * DHID + col;
                Whs_hi[o] = hb;
                Whs_lo[o] = f2bf(v - bf2f(hb));
            }
        } else if (w == 1) {
#pragma unroll
            for (int r = 0; r < 4; ++r) {
                float v = acc[r];
                unsigned short hb = f2bf(v);
                size_t o = (size_t)(b * NTOK + nr + r) * DHID + (col - 64);
                Wht_hi[o] = hb;
                Wht_lo[o] = f2bf(v - bf2f(hb));
            }
        } else {
            // permuted destination column base (keys nr..nr+3, t = r stays)
            int pcol = (nr & ~31) | ((nr & 8) << 1) | ((nr & 4) << 1) | ((nr & 16) >> 2);
            unsigned int p01 = (unsigned int)f2bf(acc[0]) | ((unsigned int)f2bf(acc[1]) << 16);
            unsigned int p23 = (unsigned int)f2bf(acc[2]) | ((unsigned int)f2bf(acc[3]) << 16);
            unsigned int* dst =
                reinterpret_cast<unsigned int*>(&WhcT[(size_t)(b * DOUT + col - 128) * NTOK + pcol]);
            dst[0] = p01;
            dst[1] = p23;
        }
    }
}

// ---------------------------------------------------------------- attn (split-K)
// grid (N/128, B, SPLIT), 256 thr, 2 blocks/CU. Wave owns 32 q-rows (groups
// A: q0+lc, B: q0+16+lc). s[kc][r] = score(q, key=16kc+4lg+r), log2 domain.
// Single-buffered LDS, two barriers/tile (write phase separate from compute).
__global__ __launch_bounds__(256, 2) void attn_kernel(const unsigned short* __restrict__ Whs_hi,
                                                      const unsigned short* __restrict__ Whs_lo,
                                                      const unsigned short* __restrict__ Wht_hi,
                                                      const unsigned short* __restrict__ Wht_lo,
                                                      const unsigned short* __restrict__ WhcT,
                                                      const unsigned int* __restrict__ bits,
                                                      unsigned short* __restrict__ po,
                                                      float* __restrict__ pm,
                                                      float* __restrict__ pl) {
    __shared__ unsigned short Kh_lds[64][72];
    __shared__ unsigned short Kl_lds[64][72];
    __shared__ unsigned short V_lds[128][72];  // [d][slot] (slots pre-permuted)

    int tid = threadIdx.x;
    int b = blockIdx.y;
    int split = blockIdx.z;
    int kbase = split * (ITERS * 64);
    int lane = tid & 63, lg = lane >> 4, lc = lane & 15;
    int q0 = blockIdx.x * 128 + (tid >> 6) * 32;
    int nA = q0 + lc, nB = q0 + 16 + lc;

    const unsigned short* qAH = Whs_hi + (size_t)(b * NTOK + nA) * DHID;
    const unsigned short* qAL = Whs_lo + (size_t)(b * NTOK + nA) * DHID;
    const unsigned short* qBH = Whs_hi + (size_t)(b * NTOK + nB) * DHID;
    const unsigned short* qBL = Whs_lo + (size_t)(b * NTOK + nB) * DHID;
    short8 qAh0 = *reinterpret_cast<const short8*>(qAH + lg * 8);
    short8 qAh1 = *reinterpret_cast<const short8*>(qAH + 32 + lg * 8);
    short8 qAl0 = *reinterpret_cast<const short8*>(qAL + lg * 8);
    short8 qAl1 = *reinterpret_cast<const short8*>(qAL + 32 + lg * 8);
    short8 qBh0 = *reinterpret_cast<const short8*>(qBH + lg * 8);
    short8 qBh1 = *reinterpret_cast<const short8*>(qBH + 32 + lg * 8);
    short8 qBl0 = *reinterpret_cast<const short8*>(qBL + lg * 8);
    short8 qBl1 = *reinterpret_cast<const short8*>(qBL + 32 + lg * 8);

    floatx4 o0[8], o1[8];
#pragma unroll
    for (int dt = 0; dt < 8; ++dt) {
        o0[dt] = (floatx4){0.f, 0.f, 0.f, 0.f};
        o1[dt] = (floatx4){0.f, 0.f, 0.f, 0.f};
    }
    float mA = NEG_BIG, lA = 0.f, mB = NEG_BIG, lB = 0.f;

    int kkey = tid >> 2, koff = (tid & 3) * 16;
    int vd = tid >> 1, va = tid & 1;

    short8 krH0, krH1, krL0, krL1, vr0, vr1, vr2, vr3;
    unsigned int mwA0, mwA1, mwB0, mwB1;

    {  // prologue: load tile 0
        int kb = kbase;
        const unsigned short* ksrcH = Wht_hi + (size_t)(b * NTOK + kb + kkey) * DHID + koff;
        const unsigned short* ksrcL = Wht_lo + (size_t)(b * NTOK + kb + kkey) * DHID + koff;
        krH0 = *reinterpret_cast<const short8*>(ksrcH);
        krH1 = *reinterpret_cast<const short8*>(ksrcH + 8);
        krL0 = *reinterpret_cast<const short8*>(ksrcL);
        krL1 = *reinterpret_cast<const short8*>(ksrcL + 8);
        const unsigned short* vsrc = WhcT + (size_t)(b * DOUT + vd) * NTOK + kb + va * 32;
        vr0 = *reinterpret_cast<const short8*>(vsrc);
        vr1 = *reinterpret_cast<const short8*>(vsrc + 8);
        vr2 = *reinterpret_cast<const short8*>(vsrc + 16);
        vr3 = *reinterpret_cast<const short8*>(vsrc + 24);
        mwA0 = bits[nA * NWRD + (kb >> 5)];
        mwA1 = bits[nA * NWRD + (kb >> 5) + 1];
        mwB0 = bits[nB * NWRD + (kb >> 5)];
        mwB1 = bits[nB * NWRD + (kb >> 5) + 1];
    }

    for (int it = 0; it < ITERS; ++it) {
        __syncthreads();  // previous tile's compute done
        *reinterpret_cast<short8*>(&Kh_lds[kkey][koff]) = krH0;
        *reinterpret_cast<short8*>(&Kh_lds[kkey][koff + 8]) = krH1;
        *reinterpret_cast<short8*>(&Kl_lds[kkey][koff]) = krL0;
        *reinterpret_cast<short8*>(&Kl_lds[kkey][koff + 8]) = krL1;
        // V staging: straight copy (slots pre-permuted in WhcT by prep)
        *reinterpret_cast<short8*>(&V_lds[vd][va * 32]) = vr0;
        *reinterpret_cast<short8*>(&V_lds[vd][va * 32 + 8]) = vr1;
        *reinterpret_cast<short8*>(&V_lds[vd][va * 32 + 16]) = vr2;
        *reinterpret_cast<short8*>(&V_lds[vd][va * 32 + 24]) = vr3;
        __syncthreads();  // tile visible

        // S^T = K Q^T, hi/lo cross terms, both q-groups share the K fragments
        floatx4 s0[4], s1[4];
        __builtin_amdgcn_s_setprio(1);
#pragma unroll
        for (int kc = 0; kc < 4; ++kc) {
            short8 kh0 = *reinterpret_cast<const short8*>(&Kh_lds[kc * 16 + lc][lg * 8]);
            short8 kh1 = *reinterpret_cast<const short8*>(&Kh_lds[kc * 16 + lc][32 + lg * 8]);
            short8 kl0 = *reinterpret_cast<const short8*>(&Kl_lds[kc * 16 + lc][lg * 8]);
            short8 kl1 = *reinterpret_cast<const short8*>(&Kl_lds[kc * 16 + lc][32 + lg * 8]);
            floatx4 a0 = {0.f, 0.f, 0.f, 0.f};
            a0 = mfma16(kh0, qAh0, a0);
            a0 = mfma16(kh1, qAh1, a0);
            a0 = mfma16(kh0, qAl0, a0);
            a0 = mfma16(kh1, qAl1, a0);
            a0 = mfma16(kl0, qAh0, a0);
            a0 = mfma16(kl1, qAh1, a0);
            s0[kc] = a0;
            floatx4 a1 = {0.f, 0.f, 0.f, 0.f};
            a1 = mfma16(kh0, qBh0, a1);
            a1 = mfma16(kh1, qBh1, a1);
            a1 = mfma16(kh0, qBl0, a1);
            a1 = mfma16(kh1, qBl1, a1);
            a1 = mfma16(kl0, qBh0, a1);
            a1 = mfma16(kl1, qBh1, a1);
            s1[kc] = a1;
        }
        __builtin_amdgcn_s_setprio(0);

        // adjacency mask: key = 16kc+4lg+r -> word kc>>1, bit 16*(kc&1)+4lg+r
#pragma unroll
        for (int kc = 0; kc < 4; ++kc) {
            unsigned int wA = (kc & 2) ? mwA1 : mwA0;
            unsigned int wB = (kc & 2) ? mwB1 : mwB0;
#pragma unroll
            for (int r = 0; r < 4; ++r) {
                int bit = 16 * (kc & 1) + 4 * lg + r;
                if (!((wA >> bit) & 1u)) s0[kc][r] = NEG_BIG;
                if (!((wB >> bit) & 1u)) s1[kc][r] = NEG_BIG;
            }
        }

        // prefetch next tile (global -> reg, hidden under softmax+PV)
        if (it + 1 < ITERS) {
            int kb = kbase + (it + 1) * 64;
            const unsigned short* ksrcH = Wht_hi + (size_t)(b * NTOK + kb + kkey) * DHID + koff;
            const unsigned short* ksrcL = Wht_lo + (size_t)(b * NTOK + kb + kkey) * DHID + koff;
            krH0 = *reinterpret_cast<const short8*>(ksrcH);
            krH1 = *reinterpret_cast<const short8*>(ksrcH + 8);
            krL0 = *reinterpret_cast<const short8*>(ksrcL);
            krL1 = *reinterpret_cast<const short8*>(ksrcL + 8);
            const unsigned short* vsrc = WhcT + (size_t)(b * DOUT + vd) * NTOK + kb + va * 32;
            vr0 = *reinterpret_cast<const short8*>(vsrc);
            vr1 = *reinterpret_cast<const short8*>(vsrc + 8);
            vr2 = *reinterpret_cast<const short8*>(vsrc + 16);
            vr3 = *reinterpret_cast<const short8*>(vsrc + 24);
            mwA0 = bits[nA * NWRD + (kb >> 5)];
            mwA1 = bits[nA * NWRD + (kb >> 5) + 1];
            mwB0 = bits[nB * NWRD + (kb >> 5)];
            mwB1 = bits[nB * NWRD + (kb >> 5) + 1];
        }

        // online softmax (log2 domain, raw v_exp_f32) + exact defer-rescale, A
        {
            float vm = s0[0][0];
#pragma unroll
            for (int kc = 0; kc < 4; ++kc)
#pragma unroll
                for (int r = 0; r < 4; ++r) vm = fmaxf(vm, s0[kc][r]);
            vm = fmaxf(vm, __shfl_xor(vm, 16));
            vm = fmaxf(vm, __shfl_xor(vm, 32));
            bool skip = __all(vm <= mA + 4.0f);
            float mn = skip ? mA : fmaxf(mA, vm);
            float rs = 0.f;
#pragma unroll
            for (int kc = 0; kc < 4; ++kc)
#pragma unroll
                for (int r = 0; r < 4; ++r) {
                    float p = ex2(s0[kc][r] - mn);
                    s0[kc][r] = p;
                    rs += p;
                }
            rs += __shfl_xor(rs, 16);
            rs += __shfl_xor(rs, 32);
            if (!skip) {
                float sc = ex2(mA - mn);
                lA = lA * sc + rs;
                mA = mn;
                float sc4[4];
#pragma unroll
                for (int r = 0; r < 4; ++r) sc4[r] = __shfl(sc, (lane & 48) + 4 * lg + r);
#pragma unroll
                for (int dt = 0; dt < 8; ++dt)
#pragma unroll
                    for (int r = 0; r < 4; ++r) o0[dt][r] *= sc4[r];
            } else {
                lA += rs;
            }
        }
        // group B
        {
            float vm = s1[0][0];
#pragma unroll
            for (int kc = 0; kc < 4; ++kc)
#pragma unroll
                for (int r = 0; r < 4; ++r) vm = fmaxf(vm, s1[kc][r]);
            vm = fmaxf(vm, __shfl_xor(vm, 16));
            vm = fmaxf(vm, __shfl_xor(vm, 32));
            bool skip = __all(vm <= mB + 4.0f);
            float mn = skip ? mB : fmaxf(mB, vm);
            float rs = 0.f;
#pragma unroll
            for (int kc = 0; kc < 4; ++kc)
#pragma unroll
                for (int r = 0; r < 4; ++r) {
                    float p = ex2(s1[kc][r] - mn);
                    s1[kc][r] = p;
                    rs += p;
                }
            rs += __shfl_xor(rs, 16);
            rs += __shfl_xor(rs, 32);
            if (!skip) {
                float sc = ex2(mB - mn);
                lB = lB * sc + rs;
                mB = mn;
                float sc4[4];
#pragma unroll
                for (int r = 0; r < 4; ++r) sc4[r] = __shfl(sc, (lane & 48) + 4 * lg + r);
#pragma unroll
                for (int dt = 0; dt < 8; ++dt)
#pragma unroll
                    for (int r = 0; r < 4; ++r) o1[dt][r] *= sc4[r];
            } else {
                lB += rs;
            }
        }

        // pack PV A-operands in-register
        unsigned int pw[8];
        pw[0] = pk2(s0[0][0], s0[0][1]); pw[1] = pk2(s0[0][2], s0[0][3]);
        pw[2] = pk2(s0[1][0], s0[1][1]); pw[3] = pk2(s0[1][2], s0[1][3]);
        pw[4] = pk2(s0[2][0], s0[2][1]); pw[5] = pk2(s0[2][2], s0[2][3]);
        pw[6] = pk2(s0[3][0], s0[3][1]); pw[7] = pk2(s0[3][2], s0[3][3]);
        short8 paA0 = __builtin_bit_cast(short8, *reinterpret_cast<uint4*>(&pw[0]));
        short8 paA1 = __builtin_bit_cast(short8, *reinterpret_cast<uint4*>(&pw[4]));
        pw[0] = pk2(s1[0][0], s1[0][1]); pw[1] = pk2(s1[0][2], s1[0][3]);
        pw[2] = pk2(s1[1][0], s1[1][1]); pw[3] = pk2(s1[1][2], s1[1][3]);
        pw[4] = pk2(s1[2][0], s1[2][1]); pw[5] = pk2(s1[2][2], s1[2][3]);
        pw[6] = pk2(s1[3][0], s1[3][1]); pw[7] = pk2(s1[3][2], s1[3][3]);
        short8 paB0 = __builtin_bit_cast(short8, *reinterpret_cast<uint4*>(&pw[0]));
        short8 paB1 = __builtin_bit_cast(short8, *reinterpret_cast<uint4*>(&pw[4]));

        // O += P V  (B col = lc = d, k = permuted slots; vf shared by both qg)
        __builtin_amdgcn_s_setprio(1);
#pragma unroll
        for (int dt = 0; dt < 8; ++dt) {
            short8 vf0 = *reinterpret_cast<const short8*>(&V_lds[dt * 16 + lc][lg * 8]);
            o0[dt] = mfma16(paA0, vf0, o0[dt]);
            o1[dt] = mfma16(paB0, vf0, o1[dt]);
        }
#pragma unroll
        for (int dt = 0; dt < 8; ++dt) {
            short8 vf1 = *reinterpret_cast<const short8*>(&V_lds[dt * 16 + lc][32 + lg * 8]);
            o0[dt] = mfma16(paA1, vf1, o0[dt]);
            o1[dt] = mfma16(paB1, vf1, o1[dt]);
        }
        __builtin_amdgcn_s_setprio(0);
    }

    // epilogue (m in log2 domain): o rows are q = q0+16qg+4lg+r; state at lc
    {
        float m4[4], l4[4];
#pragma unroll
        for (int r = 0; r < 4; ++r) {
            int src = (lane & 48) + 4 * lg + r;
            m4[r] = __shfl(mA, src);
            l4[r] = __shfl(lA, src);
        }
#pragma unroll
        for (int r = 0; r < 4; ++r) {
            size_t row = (size_t)(split * BATCH + b) * NTOK + q0 + 4 * lg + r;
            unsigned short* prow = po + row * DOUT;
#pragma unroll
            for (int dt = 0; dt < 8; ++dt) prow[dt * 16 + lc] = f2bf(o0[dt][r]);
            if (lc == 0) {
                pm[row] = m4[r];
                pl[row] = l4[r];
            }
        }
#pragma unroll
        for (int r = 0; r < 4; ++r) {
            int src = (lane & 48) + 4 * lg + r;
            m4[r] = __shfl(mB, src);
            l4[r] = __shfl(lB, src);
        }
#pragma unroll
        for (int r = 0; r < 4; ++r) {
            size_t row = (size_t)(split * BATCH + b) * NTOK + q0 + 16 + 4 * lg + r;
            unsigned short* prow = po + row * DOUT;
#pragma unroll
            for (int dt = 0; dt < 8; ++dt) prow[dt * 16 + lc] = f2bf(o1[dt][r]);
            if (lc == 0) {
                pm[row] = m4[r];
                pl[row] = l4[r];
            }
        }
    }
}

// ---------------------------------------------------------------- merge
__global__ __launch_bounds__(256) void merge_kernel(const unsigned short* __restrict__ po,
                                                    const float* __restrict__ pm,
                                                    const float* __restrict__ pl,
                                                    float* __restrict__ out) {
    int idx = blockIdx.x * 256 + threadIdx.x;
    int d = idx & (DOUT - 1);
    size_t bn = (size_t)(idx >> 7);
    const size_t BN = (size_t)BATCH * NTOK;

    float ms[SPLIT];
#pragma unroll
    for (int s = 0; s < SPLIT; ++s) ms[s] = pm[s * BN + bn];
    float M = ms[0];
#pragma unroll
    for (int s = 1; s < SPLIT; ++s) M = fmaxf(M, ms[s]);
    float L = 0.f, acc = 0.f;
#pragma unroll
    for (int s = 0; s < SPLIT; ++s) {
        float e = ex2(ms[s] - M);
        L += pl[s * BN + bn] * e;
        acc += bf2f(po[(s * BN + bn) * DOUT + d]) * e;
    }
    out[idx] = acc / L;
}

// ---------------------------------------------------------------- launch
extern "C" void kernel_launch(void* const* d_in, const int* in_sizes, int n_in,
                              void* d_out, int out_size, void* d_ws, size_t ws_size,
                              hipStream_t stream) {
    const float* h   = (const float*)d_in[0];
    const int*   adj = (const int*)d_in[1];
    const float* Ws  = (const float*)d_in[2];
    const float* Wt  = (const float*)d_in[3];
    const float* Wc  = (const float*)d_in[4];
    float* out = (float*)d_out;

    // workspace layout (~31 MiB)
    size_t nq = (size_t)BATCH * NTOK * DHID;
    unsigned short* Whs_hi = (unsigned short*)d_ws;                                // 2 MiB
    unsigned short* Whs_lo = Whs_hi + nq;                                          // 2 MiB
    unsigned short* Wht_hi = Whs_lo + nq;                                          // 2 MiB
    unsigned short* Wht_lo = Wht_hi + nq;                                          // 2 MiB
    unsigned short* WhcT   = Wht_lo + nq;                                          // 4 MiB
    unsigned int*   bits   = (unsigned int*)(WhcT + (size_t)BATCH * DOUT * NTOK);  // 2 MiB
    unsigned short* WT_hi  = (unsigned short*)(bits + (size_t)NTOK * NWRD);        // 64 KiB
    unsigned short* WT_lo  = WT_hi + 256 * DIN;                                    // 32 KiB
    unsigned short* po     = WT_lo + 128 * DIN;                                    // 16 MiB
    float*          pm     = (float*)(po + (size_t)SPLIT * BATCH * NTOK * DOUT);   // 256 KiB
    float*          pl     = pm + (size_t)SPLIT * BATCH * NTOK;                    // 256 KiB

    pack_adj_kernel<<<dim3(NTOK * NWRD / 256), dim3(256), 0, stream>>>(adj, bits);
    conv_w_kernel<<<dim3(128), dim3(256), 0, stream>>>(Ws, Wt, Wc, WT_hi, WT_lo);
    prep_kernel<<<dim3(NTOK / 16, BATCH), dim3(256), 0, stream>>>(
        h, WT_hi, WT_lo, Whs_hi, Whs_lo, Wht_hi, Wht_lo, WhcT);
    attn_kernel<<<dim3(NTOK / 128, BATCH, SPLIT), dim3(256), 0, stream>>>(
        Whs_hi, Whs_lo, Wht_hi, Wht_lo, WhcT, bits, po, pm, pl);
    merge_kernel<<<dim3(BATCH * NTOK * DOUT / 256), dim3(256), 0, stream>>>(po, pm, pl, out);
}